// Round 3
// baseline (1415.234 us; speedup 1.0000x reference)
//
#include <hip/hip_runtime.h>
#include <hip/hip_bf16.h>
#include <math.h>

#define IGNORE_INDEX (-100)

typedef __attribute__((ext_vector_type(8))) short short8;
typedef __attribute__((ext_vector_type(4))) float f32x4;

// Problem sizes (fixed by the reference)
static const int NTOK = 2 * 4096;   // 8192 tokens (GEMM M)
static const int DIM  = 2048;       // embed dim (GEMM K)
static const int VOC  = 32000;      // vocab (GEMM N)
static const int BM = 256, BN = 256;
static const int KH = 32;           // K per slot
static const int NPH = DIM / KH;    // 64 slots
static const int NVT = VOC / BN;    // 125 vocab tiles
static const int MT  = NTOK / BM;   // 32 m tiles

// ---------------- helpers ----------------

__device__ inline unsigned short f2bf(float f) {
  unsigned u = __builtin_bit_cast(unsigned, f);
  u += 0x7fffu + ((u >> 16) & 1u);   // RNE to bf16
  return (unsigned short)(u >> 16);
}

__device__ inline void gload_lds16(const void* g, void* l) {
  __builtin_amdgcn_global_load_lds(
      (const __attribute__((address_space(1))) void*)g,
      (__attribute__((address_space(3))) void*)l,
      16, 0, 0);
}

// ---------------- kernel 1: fp32 -> bf16 cast ----------------

__global__ void cast_f32_bf16(const float* __restrict__ in,
                              short* __restrict__ out, long n8) {
  long i0 = (long)blockIdx.x * blockDim.x + threadIdx.x;
  long stride = (long)gridDim.x * blockDim.x;
  for (long i = i0; i < n8; i += stride) {
    const float4* p = (const float4*)(in + i * 8);
    float4 a = p[0], b = p[1];
    short8 o;
    o[0] = (short)f2bf(a.x); o[1] = (short)f2bf(a.y);
    o[2] = (short)f2bf(a.z); o[3] = (short)f2bf(a.w);
    o[4] = (short)f2bf(b.x); o[5] = (short)f2bf(b.y);
    o[6] = (short)f2bf(b.z); o[7] = (short)f2bf(b.w);
    *(short8*)(out + i * 8) = o;
  }
}

// ---------------- kernel 2: 256x256 MFMA GEMM, fragment-major LDS, 2 sub-phases/slot ----------------
// LDS: A = 4 slots x 16KB at smem[0], B = 4 slots x 16KB at smem[64K]. 128KB dynamic.
// Fragment-major slot layout: frag f (16 rows x 32 k) at slot*16384 + f*1024 + lane*16.
// Staging: per-lane GLOBAL source supplies frag element (li=row, lg=16B k-chunk);
// LDS dest is wave-uniform base -> linear lane*16 write. Both write and read are
// lane-linear => zero bank conflicts by construction.

#define VM8  asm volatile("s_waitcnt vmcnt(8)" ::: "memory")
#define VM4  asm volatile("s_waitcnt vmcnt(4)" ::: "memory")
#define VM0  asm volatile("s_waitcnt vmcnt(0)" ::: "memory")
#define BARRIER asm volatile("s_barrier" ::: "memory")
#define LGKM0 asm volatile("s_waitcnt lgkmcnt(0)" ::: "memory")

#define STAGE_A(SLOT) do { \
  gload_lds16(aS0, stA0 + (SLOT) * 16384); \
  gload_lds16(aS1, stA1 + (SLOT) * 16384); \
  aS0 += KH; aS1 += KH; } while (0)

#define STAGE_B(SLOT) do { \
  gload_lds16(bS0, stB0 + (SLOT) * 16384); \
  gload_lds16(bS1, stB1 + (SLOT) * 16384); \
  bS0 += KH; bS1 += KH; } while (0)

__launch_bounds__(512, 2)
__global__ void lce_gemm(const short* __restrict__ xb, const short* __restrict__ wb,
                         float* __restrict__ pmax, float* __restrict__ psum) {
  extern __shared__ char smem[];
  char* smA = smem;
  char* smB = smem + 65536;

  // XCD-aware swizzle (nwg = 4000, divisible by 8), mt-minor for W-panel L2 reuse
  const int nwg = NVT * MT;            // 4000
  const int cpx = nwg >> 3;            // 500
  const int bid = blockIdx.x;
  const int swz = (bid & 7) * cpx + (bid >> 3);
  const int vt = swz / MT;
  const int mt = swz % MT;
  const int m0 = mt * BM;
  const int v0 = vt * BN;

  const int tid = threadIdx.x;
  const int lane = tid & 63;
  const int w = tid >> 6;              // 0..7
  const int wr = w >> 2, wc = w & 3;   // 2 x 4 wave grid; wave tile 128x64
  const int li = lane & 15, lg = lane >> 4;

  f32x4 acc[8][4];
  const f32x4 z = {0.f, 0.f, 0.f, 0.f};
#pragma unroll
  for (int i = 0; i < 8; ++i)
#pragma unroll
    for (int j = 0; j < 4; ++j) acc[i][j] = z;

  // staging sources: wave w stages A frags {2w, 2w+1} and B frags {2w, 2w+1}
  // frag f element for lane: row = f*16 + li, k-bytes = lg*16 (8 bf16)
  const short* aS0 = xb + (long)(m0 + 2 * w * 16 + li) * DIM + lg * 8;
  const short* aS1 = xb + (long)(m0 + (2 * w + 1) * 16 + li) * DIM + lg * 8;
  const short* bS0 = wb + (long)(v0 + 2 * w * 16 + li) * DIM + lg * 8;
  const short* bS1 = wb + (long)(v0 + (2 * w + 1) * 16 + li) * DIM + lg * 8;
  char* stA0 = smA + 2 * w * 1024;
  char* stA1 = smA + (2 * w + 1) * 1024;
  char* stB0 = smB + 2 * w * 1024;
  char* stB1 = smB + (2 * w + 1) * 1024;

  // ds_read offsets: wave reads A frags wr*8+i, B frags wc*4+j; lane-linear
  const int aOff = wr * 8192 + lane * 16;
  const int bOff = wc * 4096 + lane * 16;

  // ---- prologue: stage slots 0,1,2 (12 loads/wave); slot 0 ready at vmcnt(8) ----
  STAGE_A(0); STAGE_B(0);
  STAGE_A(1); STAGE_B(1);
  STAGE_A(2); STAGE_B(2);
  VM8;
  BARRIER;

  // ---- main loop: 64 slots x 2 sub-phases of 16 MFMA ----
#pragma unroll 1
  for (int n = 0; n < NPH; ++n) {
    const int slot = n & 3;
    const char* Ap = smA + slot * 16384 + aOff;
    const char* Bp = smB + slot * 16384 + bOff;
    const bool stg = (n < NPH - 3);

    // sub-phase 0: 8 ds_reads + stage A-pair; MFMA quadrant i=0..3
    short8 a0 = *(const short8*)(Ap);
    short8 a1 = *(const short8*)(Ap + 1024);
    short8 a2 = *(const short8*)(Ap + 2048);
    short8 a3 = *(const short8*)(Ap + 3072);
    short8 b0 = *(const short8*)(Bp);
    short8 b1 = *(const short8*)(Bp + 1024);
    short8 b2 = *(const short8*)(Bp + 2048);
    short8 b3 = *(const short8*)(Bp + 3072);
    if (stg) STAGE_A((n + 3) & 3);
    BARRIER;
    LGKM0;
    __builtin_amdgcn_s_setprio(1);
    acc[0][0] = __builtin_amdgcn_mfma_f32_16x16x32_bf16(a0, b0, acc[0][0], 0, 0, 0);
    acc[0][1] = __builtin_amdgcn_mfma_f32_16x16x32_bf16(a0, b1, acc[0][1], 0, 0, 0);
    acc[0][2] = __builtin_amdgcn_mfma_f32_16x16x32_bf16(a0, b2, acc[0][2], 0, 0, 0);
    acc[0][3] = __builtin_amdgcn_mfma_f32_16x16x32_bf16(a0, b3, acc[0][3], 0, 0, 0);
    acc[1][0] = __builtin_amdgcn_mfma_f32_16x16x32_bf16(a1, b0, acc[1][0], 0, 0, 0);
    acc[1][1] = __builtin_amdgcn_mfma_f32_16x16x32_bf16(a1, b1, acc[1][1], 0, 0, 0);
    acc[1][2] = __builtin_amdgcn_mfma_f32_16x16x32_bf16(a1, b2, acc[1][2], 0, 0, 0);
    acc[1][3] = __builtin_amdgcn_mfma_f32_16x16x32_bf16(a1, b3, acc[1][3], 0, 0, 0);
    acc[2][0] = __builtin_amdgcn_mfma_f32_16x16x32_bf16(a2, b0, acc[2][0], 0, 0, 0);
    acc[2][1] = __builtin_amdgcn_mfma_f32_16x16x32_bf16(a2, b1, acc[2][1], 0, 0, 0);
    acc[2][2] = __builtin_amdgcn_mfma_f32_16x16x32_bf16(a2, b2, acc[2][2], 0, 0, 0);
    acc[2][3] = __builtin_amdgcn_mfma_f32_16x16x32_bf16(a2, b3, acc[2][3], 0, 0, 0);
    acc[3][0] = __builtin_amdgcn_mfma_f32_16x16x32_bf16(a3, b0, acc[3][0], 0, 0, 0);
    acc[3][1] = __builtin_amdgcn_mfma_f32_16x16x32_bf16(a3, b1, acc[3][1], 0, 0, 0);
    acc[3][2] = __builtin_amdgcn_mfma_f32_16x16x32_bf16(a3, b2, acc[3][2], 0, 0, 0);
    acc[3][3] = __builtin_amdgcn_mfma_f32_16x16x32_bf16(a3, b3, acc[3][3], 0, 0, 0);
    __builtin_amdgcn_s_setprio(0);
    BARRIER;

    // sub-phase 1: 4 ds_reads + stage B-pair; MFMA quadrant i=4..7 (b0..b3 reused)
    short8 a4 = *(const short8*)(Ap + 4096);
    short8 a5 = *(const short8*)(Ap + 5120);
    short8 a6 = *(const short8*)(Ap + 6144);
    short8 a7 = *(const short8*)(Ap + 7168);
    if (stg) STAGE_B((n + 3) & 3);
    BARRIER;
    LGKM0;
    __builtin_amdgcn_s_setprio(1);
    acc[4][0] = __builtin_amdgcn_mfma_f32_16x16x32_bf16(a4, b0, acc[4][0], 0, 0, 0);
    acc[4][1] = __builtin_amdgcn_mfma_f32_16x16x32_bf16(a4, b1, acc[4][1], 0, 0, 0);
    acc[4][2] = __builtin_amdgcn_mfma_f32_16x16x32_bf16(a4, b2, acc[4][2], 0, 0, 0);
    acc[4][3] = __builtin_amdgcn_mfma_f32_16x16x32_bf16(a4, b3, acc[4][3], 0, 0, 0);
    acc[5][0] = __builtin_amdgcn_mfma_f32_16x16x32_bf16(a5, b0, acc[5][0], 0, 0, 0);
    acc[5][1] = __builtin_amdgcn_mfma_f32_16x16x32_bf16(a5, b1, acc[5][1], 0, 0, 0);
    acc[5][2] = __builtin_amdgcn_mfma_f32_16x16x32_bf16(a5, b2, acc[5][2], 0, 0, 0);
    acc[5][3] = __builtin_amdgcn_mfma_f32_16x16x32_bf16(a5, b3, acc[5][3], 0, 0, 0);
    acc[6][0] = __builtin_amdgcn_mfma_f32_16x16x32_bf16(a6, b0, acc[6][0], 0, 0, 0);
    acc[6][1] = __builtin_amdgcn_mfma_f32_16x16x32_bf16(a6, b1, acc[6][1], 0, 0, 0);
    acc[6][2] = __builtin_amdgcn_mfma_f32_16x16x32_bf16(a6, b2, acc[6][2], 0, 0, 0);
    acc[6][3] = __builtin_amdgcn_mfma_f32_16x16x32_bf16(a6, b3, acc[6][3], 0, 0, 0);
    acc[7][0] = __builtin_amdgcn_mfma_f32_16x16x32_bf16(a7, b0, acc[7][0], 0, 0, 0);
    acc[7][1] = __builtin_amdgcn_mfma_f32_16x16x32_bf16(a7, b1, acc[7][1], 0, 0, 0);
    acc[7][2] = __builtin_amdgcn_mfma_f32_16x16x32_bf16(a7, b2, acc[7][2], 0, 0, 0);
    acc[7][3] = __builtin_amdgcn_mfma_f32_16x16x32_bf16(a7, b3, acc[7][3], 0, 0, 0);
    __builtin_amdgcn_s_setprio(0);
    if (n < NPH - 3) { VM8; }
    else if (n == NPH - 3) { VM4; }
    else if (n == NPH - 2) { VM0; }
    BARRIER;
  }

  // ---- epilogue: per-row max & sum(exp) over this tile's 256 cols ----
  // C/D layout: col = li, row(within 16x16) = lg*4 + r
  float* sm_m = (float*)smem;          // [4][256]
  float* sm_s = (float*)(smem + 4096); // [4][256]
#pragma unroll
  for (int i = 0; i < 8; ++i) {
#pragma unroll
    for (int r = 0; r < 4; ++r) {
      float m = fmaxf(fmaxf(acc[i][0][r], acc[i][1][r]),
                      fmaxf(acc[i][2][r], acc[i][3][r]));
#pragma unroll
      for (int mk = 1; mk < 16; mk <<= 1) m = fmaxf(m, __shfl_xor(m, mk));
      float s = __expf(acc[i][0][r] - m) + __expf(acc[i][1][r] - m) +
                __expf(acc[i][2][r] - m) + __expf(acc[i][3][r] - m);
#pragma unroll
      for (int mk = 1; mk < 16; mk <<= 1) s += __shfl_xor(s, mk);
      if (li == 0) {
        int R = wr * 128 + i * 16 + lg * 4 + r;
        sm_m[wc * 256 + R] = m;
        sm_s[wc * 256 + R] = s;
      }
    }
  }
  __syncthreads();
  if (tid < BM) {
    float ma = sm_m[tid], mb = sm_m[256 + tid], mc = sm_m[512 + tid], md = sm_m[768 + tid];
    float gm = fmaxf(fmaxf(ma, mb), fmaxf(mc, md));
    float gs = sm_s[tid] * __expf(ma - gm) + sm_s[256 + tid] * __expf(mb - gm) +
               sm_s[512 + tid] * __expf(mc - gm) + sm_s[768 + tid] * __expf(md - gm);
    long row = (long)(m0 + tid);
    pmax[row * NVT + vt] = gm;
    psum[row * NVT + vt] = gs;
  }
}

// ---------------- kernel 3: per-token LSE combine + exact fp32 target dot ----------------

__global__ void token_reduce(const float* __restrict__ x, const float* __restrict__ wgt,
                             const int* __restrict__ tgt,
                             const float* __restrict__ pmax, const float* __restrict__ psum,
                             float* __restrict__ nll, float* __restrict__ validf) {
  const int n = blockIdx.x;
  const int tid = threadIdx.x;
  const int lane = tid & 63;
  const int w = tid >> 6;
  __shared__ float smr[4];

  const int t = tgt[n];
  const bool valid = (t != IGNORE_INDEX);
  const int ts = valid ? t : 0;

  // exact fp32 target logit
  const float4* xr = (const float4*)(x + (long)n * DIM);
  const float4* wr = (const float4*)(wgt + (long)ts * DIM);
  float d = 0.f;
  for (int i = tid; i < DIM / 4; i += blockDim.x) {
    float4 a = xr[i], b = wr[i];
    d += a.x * b.x + a.y * b.y + a.z * b.z + a.w * b.w;
  }

  // LSE over 125 partials
  float m = (tid < NVT) ? pmax[(long)n * NVT + tid] : -INFINITY;
  float t1 = m;
#pragma unroll
  for (int mk = 1; mk < 64; mk <<= 1) t1 = fmaxf(t1, __shfl_xor(t1, mk));
  if (lane == 0) smr[w] = t1;
  __syncthreads();
  const float gm = fmaxf(fmaxf(smr[0], smr[1]), fmaxf(smr[2], smr[3]));
  __syncthreads();

  float se = (tid < NVT) ? psum[(long)n * NVT + tid] * __expf(m - gm) : 0.f;
#pragma unroll
  for (int mk = 1; mk < 64; mk <<= 1) se += __shfl_xor(se, mk);
  if (lane == 0) smr[w] = se;
  __syncthreads();
  const float gs = smr[0] + smr[1] + smr[2] + smr[3];
  __syncthreads();

#pragma unroll
  for (int mk = 1; mk < 64; mk <<= 1) d += __shfl_xor(d, mk);
  if (lane == 0) smr[w] = d;
  __syncthreads();
  const float gd = smr[0] + smr[1] + smr[2] + smr[3];

  if (tid == 0) {
    nll[n] = valid ? (gm + logf(gs) - gd) : 0.f;
    validf[n] = valid ? 1.f : 0.f;
  }
}

// ---------------- kernel 4: deterministic final mean ----------------

__global__ void final_reduce(const float* __restrict__ nll, const float* __restrict__ validf,
                             float* __restrict__ out, int n) {
  const int tid = threadIdx.x;
  const int lane = tid & 63;
  const int w = tid >> 6;
  __shared__ float sm1[4], sm2[4];
  float s = 0.f, c = 0.f;
  for (int i = tid; i < n; i += blockDim.x) { s += nll[i]; c += validf[i]; }
#pragma unroll
  for (int mk = 1; mk < 64; mk <<= 1) { s += __shfl_xor(s, mk); c += __shfl_xor(c, mk); }
  if (lane == 0) { sm1[w] = s; sm2[w] = c; }
  __syncthreads();
  if (tid == 0) {
    float ts = sm1[0] + sm1[1] + sm1[2] + sm1[3];
    float tc = sm2[0] + sm2[1] + sm2[2] + sm2[3];
    out[0] = ts / fmaxf(tc, 1.0f);
  }
}

// ---------------- launch ----------------

extern "C" void kernel_launch(void* const* d_in, const int* in_sizes, int n_in,
                              void* d_out, int out_size, void* d_ws, size_t ws_size,
                              hipStream_t stream) {
  const float* x = (const float*)d_in[0];     // [8192, 2048] fp32
  const float* wgt = (const float*)d_in[1];   // [32000, 2048] fp32
  const int* tgt = (const int*)d_in[2];       // [8192] int
  float* out = (float*)d_out;

  char* ws = (char*)d_ws;
  const size_t xb_off = 0;
  const size_t wb_off = (size_t)NTOK * DIM * 2;
  const size_t pm_off = wb_off + (size_t)VOC * DIM * 2;
  const size_t ps_off = pm_off + (size_t)NTOK * NVT * 4;
  const size_t nl_off = ps_off + (size_t)NTOK * NVT * 4;
  const size_t vf_off = nl_off + (size_t)NTOK * 4;
  const size_t needed = vf_off + (size_t)NTOK * 4;
  if (ws_size < needed) return;  // workspace too small: fail visibly

  short* xb = (short*)(ws + xb_off);
  short* wb = (short*)(ws + wb_off);
  float* pmax = (float*)(ws + pm_off);
  float* psum = (float*)(ws + ps_off);
  float* nllv = (float*)(ws + nl_off);
  float* vldf = (float*)(ws + vf_off);

  cast_f32_bf16<<<2048, 256, 0, stream>>>(x, xb, (long)NTOK * DIM / 8);
  cast_f32_bf16<<<4096, 256, 0, stream>>>(wgt, wb, (long)VOC * DIM / 8);

  (void)hipFuncSetAttribute((const void*)lce_gemm,
                            hipFuncAttributeMaxDynamicSharedMemorySize, 131072);
  lce_gemm<<<NVT * MT, 512, 131072, stream>>>(xb, wb, pmax, psum);

  token_reduce<<<NTOK, 256, 0, stream>>>(x, wgt, tgt, pmax, psum, nllv, vldf);
  final_reduce<<<1, 256, 0, stream>>>(nllv, vldf, out, NTOK);
}

// Round 5
// 1138.377 us; speedup vs baseline: 1.2432x; 1.2432x over previous
//
#include <hip/hip_runtime.h>
#include <hip/hip_bf16.h>
#include <math.h>

#define IGNORE_INDEX (-100)

typedef __attribute__((ext_vector_type(4))) float f32x4;

// Problem sizes (fixed by the reference)
static const int NTOK = 2 * 4096;   // 8192 tokens (GEMM M)
static const int DIM  = 2048;       // embed dim (GEMM K)
static const int VOC  = 32000;      // vocab (GEMM N)
static const int BM = 256, BN = 256;
static const int KS = 64;           // K per slot
static const int NPH = DIM / KS;    // 32 slots
static const int NVT = VOC / BN;    // 125 vocab tiles
static const int MT  = NTOK / BM;   // 32 m tiles
static const float WSCALE = 16.0f;  // W pre-scale (exact power of 2)

// ---------------- helpers ----------------

__device__ inline void gload_lds16(const void* g, void* l) {
  __builtin_amdgcn_global_load_lds(
      (const __attribute__((address_space(1))) void*)g,
      (__attribute__((address_space(3))) void*)l,
      16, 0, 0);
}

// ---------------- kernel 1: fp32 -> fp8 e4m3 cast (with scale) ----------------

__global__ void cast_f32_fp8(const float* __restrict__ in,
                             unsigned char* __restrict__ out, long n8, float scale) {
  long i0 = (long)blockIdx.x * blockDim.x + threadIdx.x;
  long stride = (long)gridDim.x * blockDim.x;
  for (long i = i0; i < n8; i += stride) {
    const float4* p = (const float4*)(in + i * 8);
    float4 a = p[0], b = p[1];
    int lo = __builtin_amdgcn_cvt_pk_fp8_f32(a.x * scale, a.y * scale, 0, false);
    lo = __builtin_amdgcn_cvt_pk_fp8_f32(a.z * scale, a.w * scale, lo, true);
    int hi = __builtin_amdgcn_cvt_pk_fp8_f32(b.x * scale, b.y * scale, 0, false);
    hi = __builtin_amdgcn_cvt_pk_fp8_f32(b.z * scale, b.w * scale, hi, true);
    int2 o; o.x = lo; o.y = hi;
    *(int2*)(out + i * 8) = o;
  }
}

// ---------------- kernel 2: 256x256 fp8 MFMA GEMM + fused row max/sumexp ----------------
// LDS: A ring = 4 slots x 16KB at smem[0]; B ring at smem[64K]. 128KB dynamic.
// Slot layout: [ks(2)][frag(16)] of 512B frags; frag byte = li*32 + (lg ^ 2*(li>>3))*8.
// Staged linearly by gload_lds16 from a pre-permuted per-lane global source
// (the XOR keeps 16B units intact: only the 16B-slot index is permuted).
// ds_read_b64 pattern is 2-way bank aliased = free.
// NOTE (R4 bug fix): global staging source advances by KS per STAGE (phase-indexed),
// NOT ring-slot-indexed — the ring slot only selects the LDS destination.

#define VM8  asm volatile("s_waitcnt vmcnt(8)" ::: "memory")
#define VM4  asm volatile("s_waitcnt vmcnt(4)" ::: "memory")
#define VM0  asm volatile("s_waitcnt vmcnt(0)" ::: "memory")
#define BARRIER asm volatile("s_barrier" ::: "memory")

#define STAGE(SLOT) do { \
  char* _dA = stA + (SLOT) * 16384; \
  char* _dB = stB + (SLOT) * 16384; \
  gload_lds16(aCur, _dA); \
  gload_lds16(aCur + 32, _dA + 8192); \
  gload_lds16(bCur, _dB); \
  gload_lds16(bCur + 32, _dB + 8192); \
  aCur += KS; bCur += KS; \
} while (0)

__launch_bounds__(512, 2)
__global__ void lce_gemm(const unsigned char* __restrict__ xq,
                         const unsigned char* __restrict__ wq,
                         float* __restrict__ pmax, float* __restrict__ psum) {
  extern __shared__ char smem[];
  char* smA = smem;
  char* smB = smem + 65536;

  // XCD-aware swizzle (nwg = 4000, divisible by 8), mt-minor
  const int nwg = NVT * MT;            // 4000
  const int cpx = nwg >> 3;            // 500
  const int bid = blockIdx.x;
  const int swz = (bid & 7) * cpx + (bid >> 3);
  const int vt = swz / MT;
  const int mt = swz % MT;
  const int m0 = mt * BM;
  const int v0 = vt * BN;

  const int tid = threadIdx.x;
  const int lane = tid & 63;
  const int w = tid >> 6;              // 0..7
  const int wr = w >> 2, wc = w & 3;   // 2 x 4 wave grid; wave tile 128x64
  const int li = lane & 15, lg = lane >> 4;

  f32x4 acc[8][4];
  const f32x4 z = {0.f, 0.f, 0.f, 0.f};
#pragma unroll
  for (int i = 0; i < 8; ++i)
#pragma unroll
    for (int j = 0; j < 4; ++j) acc[i][j] = z;

  // ---- staging source (per-lane global, pre-permuted for the lg-XOR) ----
  // lane l supplies frag f = 2w + (l>>5), row-in-frag li_s = (l>>1)&15,
  // 16B half u = l&1; global 16B-half = u ^ (li_s>>3)
  const int floc = lane >> 5;
  const int li_s = (lane >> 1) & 15;
  const int u_s = lane & 1;
  const int kb = ((u_s ^ (li_s >> 3)) << 4);   // 0 or 16 bytes within 32B ks-chunk
  const int rowoff = 32 * w + 16 * floc + li_s;
  const unsigned char* aCur = xq + (long)(m0 + rowoff) * DIM + kb;
  const unsigned char* bCur = wq + (long)(v0 + rowoff) * DIM + kb;
  char* stA = smA + w * 1024;
  char* stB = smB + w * 1024;

  // ---- ds_read per-lane offset (swizzled) ----
  const int lgs = (lg ^ ((li >> 3) << 1));
  const int aLane = li * 32 + lgs * 8;
  const char* aRd = smA + wr * 4096 + aLane;   // + slot*16384 + ks*8192 + i*512
  const char* bRd = smB + wc * 2048 + aLane;   // + slot*16384 + ks*8192 + j*512

  // ---- prologue: stage phases 0,1,2 into slots 0,1,2 (12 loads/wave) ----
  STAGE(0);
  STAGE(1);
  STAGE(2);
  VM8;
  BARRIER;

  // ---- main loop: 32 slots of K=64; 24 ds_read_b64 + 64 MFMA + counted vmcnt ----
#pragma unroll 1
  for (int n = 0; n < NPH; ++n) {
    const int slot = n & 3;
    const char* Ab = aRd + slot * 16384;
    const char* Bb = bRd + slot * 16384;

    long a0[8], a1[8], b0[4], b1[4];
#pragma unroll
    for (int i = 0; i < 8; ++i) a0[i] = *(const long*)(Ab + i * 512);
#pragma unroll
    for (int j = 0; j < 4; ++j) b0[j] = *(const long*)(Bb + j * 512);
#pragma unroll
    for (int i = 0; i < 8; ++i) a1[i] = *(const long*)(Ab + 8192 + i * 512);
#pragma unroll
    for (int j = 0; j < 4; ++j) b1[j] = *(const long*)(Bb + 8192 + j * 512);

    if (n < NPH - 3) STAGE(((n + 3) & 3));   // stages PHASE n+3 (aCur/bCur advance)
    BARRIER;
    __builtin_amdgcn_s_setprio(1);
#pragma unroll
    for (int i = 0; i < 8; ++i)
#pragma unroll
      for (int j = 0; j < 4; ++j)
        acc[i][j] = __builtin_amdgcn_mfma_f32_16x16x32_fp8_fp8(a0[i], b0[j], acc[i][j], 0, 0, 0);
#pragma unroll
    for (int i = 0; i < 8; ++i)
#pragma unroll
      for (int j = 0; j < 4; ++j)
        acc[i][j] = __builtin_amdgcn_mfma_f32_16x16x32_fp8_fp8(a1[i], b1[j], acc[i][j], 0, 0, 0);
    __builtin_amdgcn_s_setprio(0);
    if (n < NPH - 3) { VM8; }
    else if (n == NPH - 3) { VM4; }
    else if (n == NPH - 2) { VM0; }
    BARRIER;
  }

  // ---- epilogue: per-row max & sum(exp) over this tile's 256 cols; logits = acc/WSCALE ----
  // C/D layout: col = li, row(within 16x16) = lg*4 + r
  const float sc = 1.0f / WSCALE;
  float* sm_m = (float*)smem;          // [4][256]
  float* sm_s = (float*)(smem + 4096); // [4][256]
  __syncthreads();                     // loop fully drained; safe to reuse LDS
#pragma unroll
  for (int i = 0; i < 8; ++i) {
#pragma unroll
    for (int r = 0; r < 4; ++r) {
      float l0 = acc[i][0][r] * sc, l1 = acc[i][1][r] * sc;
      float l2 = acc[i][2][r] * sc, l3 = acc[i][3][r] * sc;
      float m = fmaxf(fmaxf(l0, l1), fmaxf(l2, l3));
#pragma unroll
      for (int mk = 1; mk < 16; mk <<= 1) m = fmaxf(m, __shfl_xor(m, mk));
      float s = __expf(l0 - m) + __expf(l1 - m) + __expf(l2 - m) + __expf(l3 - m);
#pragma unroll
      for (int mk = 1; mk < 16; mk <<= 1) s += __shfl_xor(s, mk);
      if (li == 0) {
        int R = wr * 128 + i * 16 + lg * 4 + r;
        sm_m[wc * 256 + R] = m;
        sm_s[wc * 256 + R] = s;
      }
    }
  }
  __syncthreads();
  if (tid < BM) {
    float ma = sm_m[tid], mb = sm_m[256 + tid], mc = sm_m[512 + tid], md = sm_m[768 + tid];
    float gm = fmaxf(fmaxf(ma, mb), fmaxf(mc, md));
    float gs = sm_s[tid] * __expf(ma - gm) + sm_s[256 + tid] * __expf(mb - gm) +
               sm_s[512 + tid] * __expf(mc - gm) + sm_s[768 + tid] * __expf(md - gm);
    long row = (long)(m0 + tid);
    pmax[row * NVT + vt] = gm;
    psum[row * NVT + vt] = gs;
  }
}

// ---------------- kernel 3: per-token LSE combine + exact fp32 target dot ----------------

__global__ void token_reduce(const float* __restrict__ x, const float* __restrict__ wgt,
                             const int* __restrict__ tgt,
                             const float* __restrict__ pmax, const float* __restrict__ psum,
                             float* __restrict__ nll, float* __restrict__ validf) {
  const int n = blockIdx.x;
  const int tid = threadIdx.x;
  const int lane = tid & 63;
  const int w = tid >> 6;
  __shared__ float smr[4];

  const int t = tgt[n];
  const bool valid = (t != IGNORE_INDEX);
  const int ts = valid ? t : 0;

  // exact fp32 target logit
  const float4* xr = (const float4*)(x + (long)n * DIM);
  const float4* wr = (const float4*)(wgt + (long)ts * DIM);
  float d = 0.f;
  for (int i = tid; i < DIM / 4; i += blockDim.x) {
    float4 a = xr[i], b = wr[i];
    d += a.x * b.x + a.y * b.y + a.z * b.z + a.w * b.w;
  }

  // LSE over 125 partials
  float m = (tid < NVT) ? pmax[(long)n * NVT + tid] : -INFINITY;
  float t1 = m;
#pragma unroll
  for (int mk = 1; mk < 64; mk <<= 1) t1 = fmaxf(t1, __shfl_xor(t1, mk));
  if (lane == 0) smr[w] = t1;
  __syncthreads();
  const float gm = fmaxf(fmaxf(smr[0], smr[1]), fmaxf(smr[2], smr[3]));
  __syncthreads();

  float se = (tid < NVT) ? psum[(long)n * NVT + tid] * __expf(m - gm) : 0.f;
#pragma unroll
  for (int mk = 1; mk < 64; mk <<= 1) se += __shfl_xor(se, mk);
  if (lane == 0) smr[w] = se;
  __syncthreads();
  const float gs = smr[0] + smr[1] + smr[2] + smr[3];
  __syncthreads();

#pragma unroll
  for (int mk = 1; mk < 64; mk <<= 1) d += __shfl_xor(d, mk);
  if (lane == 0) smr[w] = d;
  __syncthreads();
  const float gd = smr[0] + smr[1] + smr[2] + smr[3];

  if (tid == 0) {
    nll[n] = valid ? (gm + logf(gs) - gd) : 0.f;
    validf[n] = valid ? 1.f : 0.f;
  }
}

// ---------------- kernel 4: deterministic final mean ----------------

__global__ void final_reduce(const float* __restrict__ nll, const float* __restrict__ validf,
                             float* __restrict__ out, int n) {
  const int tid = threadIdx.x;
  const int lane = tid & 63;
  const int w = tid >> 6;
  __shared__ float sm1[4], sm2[4];
  float s = 0.f, c = 0.f;
  for (int i = tid; i < n; i += blockDim.x) { s += nll[i]; c += validf[i]; }
#pragma unroll
  for (int mk = 1; mk < 64; mk <<= 1) { s += __shfl_xor(s, mk); c += __shfl_xor(c, mk); }
  if (lane == 0) { sm1[w] = s; sm2[w] = c; }
  __syncthreads();
  if (tid == 0) {
    float ts = sm1[0] + sm1[1] + sm1[2] + sm1[3];
    float tc = sm2[0] + sm2[1] + sm2[2] + sm2[3];
    out[0] = ts / fmaxf(tc, 1.0f);
  }
}

// ---------------- launch ----------------

extern "C" void kernel_launch(void* const* d_in, const int* in_sizes, int n_in,
                              void* d_out, int out_size, void* d_ws, size_t ws_size,
                              hipStream_t stream) {
  const float* x = (const float*)d_in[0];     // [8192, 2048] fp32
  const float* wgt = (const float*)d_in[1];   // [32000, 2048] fp32
  const int* tgt = (const int*)d_in[2];       // [8192] int
  float* out = (float*)d_out;

  char* ws = (char*)d_ws;
  const size_t xq_off = 0;
  const size_t wq_off = (size_t)NTOK * DIM;                        // 16,777,216
  const size_t pm_off = wq_off + (size_t)VOC * DIM;                // 82,313,216
  const size_t ps_off = pm_off + (size_t)NTOK * NVT * 4;
  const size_t nl_off = ps_off + (size_t)NTOK * NVT * 4;
  const size_t vf_off = nl_off + (size_t)NTOK * 4;
  const size_t needed = vf_off + (size_t)NTOK * 4;
  if (ws_size < needed) return;  // workspace too small: fail visibly

  unsigned char* xq = (unsigned char*)(ws + xq_off);
  unsigned char* wq = (unsigned char*)(ws + wq_off);
  float* pmax = (float*)(ws + pm_off);
  float* psum = (float*)(ws + ps_off);
  float* nllv = (float*)(ws + nl_off);
  float* vldf = (float*)(ws + vf_off);

  cast_f32_fp8<<<2048, 256, 0, stream>>>(x, xq, (long)NTOK * DIM / 8, 1.0f);
  cast_f32_fp8<<<4096, 256, 0, stream>>>(wgt, wq, (long)VOC * DIM / 8, WSCALE);

  (void)hipFuncSetAttribute((const void*)lce_gemm,
                            hipFuncAttributeMaxDynamicSharedMemorySize, 131072);
  lce_gemm<<<NVT * MT, 512, 131072, stream>>>(xq, wq, pmax, psum);

  token_reduce<<<NTOK, 256, 0, stream>>>(x, wgt, tgt, pmax, psum, nllv, vldf);
  final_reduce<<<1, 256, 0, stream>>>(nllv, vldf, out, NTOK);
}

// Round 6
// 959.874 us; speedup vs baseline: 1.4744x; 1.1860x over previous
//
#include <hip/hip_runtime.h>
#include <hip/hip_bf16.h>
#include <math.h>

#define IGNORE_INDEX (-100)

typedef __attribute__((ext_vector_type(4))) float f32x4;
typedef __attribute__((ext_vector_type(2))) long lx2;   // 16B = one ds_read_b128

// Problem sizes (fixed by the reference)
static const int NTOK = 2 * 4096;   // 8192 tokens (GEMM M)
static const int DIM  = 2048;       // embed dim (GEMM K)
static const int VOC  = 32000;      // vocab (GEMM N)
static const int BM = 256, BN = 256;
static const int KS = 64;           // K per slot
static const int NPH = DIM / KS;    // 32 slots
static const int NVT = VOC / BN;    // 125 vocab tiles
static const int MT  = NTOK / BM;   // 32 m tiles
static const float WSCALE = 16.0f;  // W pre-scale (exact power of 2)

// ---------------- helpers ----------------

__device__ inline void gload_lds16(const void* g, void* l) {
  __builtin_amdgcn_global_load_lds(
      (const __attribute__((address_space(1))) void*)g,
      (__attribute__((address_space(3))) void*)l,
      16, 0, 0);
}

// ---------------- kernel 1: fp32 -> fp8 e4m3 cast (with scale) ----------------

__global__ void cast_f32_fp8(const float* __restrict__ in,
                             unsigned char* __restrict__ out, long n8, float scale) {
  long i0 = (long)blockIdx.x * blockDim.x + threadIdx.x;
  long stride = (long)gridDim.x * blockDim.x;
  for (long i = i0; i < n8; i += stride) {
    const float4* p = (const float4*)(in + i * 8);
    float4 a = p[0], b = p[1];
    int lo = __builtin_amdgcn_cvt_pk_fp8_f32(a.x * scale, a.y * scale, 0, false);
    lo = __builtin_amdgcn_cvt_pk_fp8_f32(a.z * scale, a.w * scale, lo, true);
    int hi = __builtin_amdgcn_cvt_pk_fp8_f32(b.x * scale, b.y * scale, 0, false);
    hi = __builtin_amdgcn_cvt_pk_fp8_f32(b.z * scale, b.w * scale, hi, true);
    int2 o; o.x = lo; o.y = hi;
    *(int2*)(out + i * 8) = o;
  }
}

// ---------------- kernel 2: 256x256 fp8 MFMA GEMM, fragment-major LDS, 4 fine phases/slot ----
// LDS: A ring = 4 slots x 16KB at smem[0]; B ring at smem[64K]. 128KB dynamic.
// Slot layout (fragment-major): frag f (16 rows x 64 k-bytes) at slot*16384 + f*1024;
// lane l (li=l&15 row, lg=l>>4) holds 16 contiguous global bytes [row][lg*16 .. +16).
// K-partition trick: MFMA k-tile0 = each lane's first 8B (global bytes 16*lg..+8),
// k-tile1 = second 8B. Any consistent K-partition is exact, and this one makes the
// lane's operand pair contiguous => ds_read_b128 lane-linear (measured 0 conflicts, R3)
// and global_load_lds staging with linear LDS dest.

#define VM8  asm volatile("s_waitcnt vmcnt(8)" ::: "memory")
#define VM4  asm volatile("s_waitcnt vmcnt(4)" ::: "memory")
#define VM0  asm volatile("s_waitcnt vmcnt(0)" ::: "memory")
#define BARRIER asm volatile("s_barrier" ::: "memory")
#define LGKM0 asm volatile("s_waitcnt lgkmcnt(0)" ::: "memory")

#define MM2(ii, jj, AR, BR) do { \
  acc[ii][jj] = __builtin_amdgcn_mfma_f32_16x16x32_fp8_fp8(AR[0], BR[0], acc[ii][jj], 0, 0, 0); \
  acc[ii][jj] = __builtin_amdgcn_mfma_f32_16x16x32_fp8_fp8(AR[1], BR[1], acc[ii][jj], 0, 0, 0); \
} while (0)

__launch_bounds__(512, 2)
__global__ void lce_gemm(const unsigned char* __restrict__ xq,
                         const unsigned char* __restrict__ wq,
                         float* __restrict__ pmax, float* __restrict__ psum) {
  extern __shared__ char smem[];
  char* smA = smem;
  char* smB = smem + 65536;

  // XCD-aware swizzle (nwg = 4000, divisible by 8), mt-minor
  const int nwg = NVT * MT;            // 4000
  const int cpx = nwg >> 3;            // 500
  const int bid = blockIdx.x;
  const int swz = (bid & 7) * cpx + (bid >> 3);
  const int vt = swz / MT;
  const int mt = swz % MT;
  const int m0 = mt * BM;
  const int v0 = vt * BN;

  const int tid = threadIdx.x;
  const int lane = tid & 63;
  const int w = tid >> 6;              // 0..7
  const int wr = w >> 2, wc = w & 3;   // 2 x 4 wave grid; wave tile 128x64
  const int li = lane & 15, lg = lane >> 4;

  f32x4 acc[8][4];
  const f32x4 z = {0.f, 0.f, 0.f, 0.f};
#pragma unroll
  for (int i = 0; i < 8; ++i)
#pragma unroll
    for (int j = 0; j < 4; ++j) acc[i][j] = z;

  // ---- staging: wave w stages A frags {2w,2w+1}, B frags {2w,2w+1} ----
  // per-lane global source: row = base + frag*16 + li, byte col = kt + lg*16
  const unsigned char* aS0 = xq + (long)(m0 + 2 * w * 16 + li) * DIM + lg * 16;
  const unsigned char* aS1 = xq + (long)(m0 + (2 * w + 1) * 16 + li) * DIM + lg * 16;
  const unsigned char* bS0 = wq + (long)(v0 + 2 * w * 16 + li) * DIM + lg * 16;
  const unsigned char* bS1 = wq + (long)(v0 + (2 * w + 1) * 16 + li) * DIM + lg * 16;
  char* stA = smA + 2 * w * 1024;      // frag 2w dest; 2w+1 at +1024
  char* stB = smB + 2 * w * 1024;

  // ---- ds_read bases (lane-linear) ----
  const char* aRd = smA + wr * 8192 + lane * 16;   // + slot*16384 + i*1024
  const char* bRd = smB + wc * 4096 + lane * 16;   // + slot*16384 + j*1024

  // ---- prologue: stage slots 0,1,2 (4 loads/slot/wave = 12) ----
#pragma unroll
  for (int s = 0; s < 3; ++s) {
    gload_lds16(aS0, stA + s * 16384);        aS0 += KS;
    gload_lds16(aS1, stA + s * 16384 + 1024); aS1 += KS;
    gload_lds16(bS0, stB + s * 16384);        bS0 += KS;
    gload_lds16(bS1, stB + s * 16384 + 1024); bS1 += KS;
  }
  VM8;   // slot 0's 4 loads done (8 remain outstanding)
  BARRIER;

  // ---- main loop: 32 slots x 4 fine phases of 16 MFMA ----
#pragma unroll 1
  for (int n = 0; n < NPH; ++n) {
    const int slot = n & 3;
    const int dst = (n + 3) & 3;
    const char* Ab = aRd + slot * 16384;
    const char* Bb = bRd + slot * 16384;
    const bool stg = (n < NPH - 3);

    // phase 0: read B0-3 + A0-1, stage A-even, MFMA rows 0-31
    lx2 B0 = *(const lx2*)(Bb);
    lx2 B1 = *(const lx2*)(Bb + 1024);
    lx2 B2 = *(const lx2*)(Bb + 2048);
    lx2 B3 = *(const lx2*)(Bb + 3072);
    lx2 A0 = *(const lx2*)(Ab);
    lx2 A1 = *(const lx2*)(Ab + 1024);
    if (stg) { gload_lds16(aS0, stA + dst * 16384); aS0 += KS; }
    BARRIER; LGKM0;
    __builtin_amdgcn_s_setprio(1);
    MM2(0, 0, A0, B0); MM2(0, 1, A0, B1); MM2(0, 2, A0, B2); MM2(0, 3, A0, B3);
    MM2(1, 0, A1, B0); MM2(1, 1, A1, B1); MM2(1, 2, A1, B2); MM2(1, 3, A1, B3);
    __builtin_amdgcn_s_setprio(0);
    BARRIER;

    // phase 1: read A2-3, stage A-odd, MFMA rows 32-63
    A0 = *(const lx2*)(Ab + 2048);
    A1 = *(const lx2*)(Ab + 3072);
    if (stg) { gload_lds16(aS1, stA + dst * 16384 + 1024); aS1 += KS; }
    BARRIER; LGKM0;
    __builtin_amdgcn_s_setprio(1);
    MM2(2, 0, A0, B0); MM2(2, 1, A0, B1); MM2(2, 2, A0, B2); MM2(2, 3, A0, B3);
    MM2(3, 0, A1, B0); MM2(3, 1, A1, B1); MM2(3, 2, A1, B2); MM2(3, 3, A1, B3);
    __builtin_amdgcn_s_setprio(0);
    BARRIER;

    // phase 2: read A4-5, stage B-even, MFMA rows 64-95
    A0 = *(const lx2*)(Ab + 4096);
    A1 = *(const lx2*)(Ab + 5120);
    if (stg) { gload_lds16(bS0, stB + dst * 16384); bS0 += KS; }
    BARRIER; LGKM0;
    __builtin_amdgcn_s_setprio(1);
    MM2(4, 0, A0, B0); MM2(4, 1, A0, B1); MM2(4, 2, A0, B2); MM2(4, 3, A0, B3);
    MM2(5, 0, A1, B0); MM2(5, 1, A1, B1); MM2(5, 2, A1, B2); MM2(5, 3, A1, B3);
    __builtin_amdgcn_s_setprio(0);
    BARRIER;

    // phase 3: read A6-7, stage B-odd, MFMA rows 96-127; slot-end counted vmcnt
    A0 = *(const lx2*)(Ab + 6144);
    A1 = *(const lx2*)(Ab + 7168);
    if (stg) { gload_lds16(bS1, stB + dst * 16384 + 1024); bS1 += KS; }
    BARRIER; LGKM0;
    __builtin_amdgcn_s_setprio(1);
    MM2(6, 0, A0, B0); MM2(6, 1, A0, B1); MM2(6, 2, A0, B2); MM2(6, 3, A0, B3);
    MM2(7, 0, A1, B0); MM2(7, 1, A1, B1); MM2(7, 2, A1, B2); MM2(7, 3, A1, B3);
    __builtin_amdgcn_s_setprio(0);
    if (n < NPH - 3) { VM8; }
    else if (n == NPH - 3) { VM4; }
    else if (n == NPH - 2) { VM0; }
    BARRIER;
  }

  // ---- epilogue: per-row max & sum(exp) over this tile's 256 cols; logits = acc/WSCALE ----
  // C/D layout: col = li, row(within 16x16) = lg*4 + r
  const float sc = 1.0f / WSCALE;
  float* sm_m = (float*)smem;          // [4][256]
  float* sm_s = (float*)(smem + 4096); // [4][256]
  __syncthreads();                     // loop fully drained; safe to reuse LDS
#pragma unroll
  for (int i = 0; i < 8; ++i) {
#pragma unroll
    for (int r = 0; r < 4; ++r) {
      float l0 = acc[i][0][r] * sc, l1 = acc[i][1][r] * sc;
      float l2 = acc[i][2][r] * sc, l3 = acc[i][3][r] * sc;
      float m = fmaxf(fmaxf(l0, l1), fmaxf(l2, l3));
#pragma unroll
      for (int mk = 1; mk < 16; mk <<= 1) m = fmaxf(m, __shfl_xor(m, mk));
      float s = __expf(l0 - m) + __expf(l1 - m) + __expf(l2 - m) + __expf(l3 - m);
#pragma unroll
      for (int mk = 1; mk < 16; mk <<= 1) s += __shfl_xor(s, mk);
      if (li == 0) {
        int R = wr * 128 + i * 16 + lg * 4 + r;
        sm_m[wc * 256 + R] = m;
        sm_s[wc * 256 + R] = s;
      }
    }
  }
  __syncthreads();
  if (tid < BM) {
    float ma = sm_m[tid], mb = sm_m[256 + tid], mc = sm_m[512 + tid], md = sm_m[768 + tid];
    float gm = fmaxf(fmaxf(ma, mb), fmaxf(mc, md));
    float gs = sm_s[tid] * __expf(ma - gm) + sm_s[256 + tid] * __expf(mb - gm) +
               sm_s[512 + tid] * __expf(mc - gm) + sm_s[768 + tid] * __expf(md - gm);
    long row = (long)(m0 + tid);
    pmax[row * NVT + vt] = gm;
    psum[row * NVT + vt] = gs;
  }
}

// ---------------- kernel 3: per-token LSE combine + exact fp32 target dot ----------------

__global__ void token_reduce(const float* __restrict__ x, const float* __restrict__ wgt,
                             const int* __restrict__ tgt,
                             const float* __restrict__ pmax, const float* __restrict__ psum,
                             float* __restrict__ nll, float* __restrict__ validf) {
  const int n = blockIdx.x;
  const int tid = threadIdx.x;
  const int lane = tid & 63;
  const int w = tid >> 6;
  __shared__ float smr[4];

  const int t = tgt[n];
  const bool valid = (t != IGNORE_INDEX);
  const int ts = valid ? t : 0;

  // exact fp32 target logit
  const float4* xr = (const float4*)(x + (long)n * DIM);
  const float4* wr = (const float4*)(wgt + (long)ts * DIM);
  float d = 0.f;
  for (int i = tid; i < DIM / 4; i += blockDim.x) {
    float4 a = xr[i], b = wr[i];
    d += a.x * b.x + a.y * b.y + a.z * b.z + a.w * b.w;
  }

  // LSE over 125 partials
  float m = (tid < NVT) ? pmax[(long)n * NVT + tid] : -INFINITY;
  float t1 = m;
#pragma unroll
  for (int mk = 1; mk < 64; mk <<= 1) t1 = fmaxf(t1, __shfl_xor(t1, mk));
  if (lane == 0) smr[w] = t1;
  __syncthreads();
  const float gm = fmaxf(fmaxf(smr[0], smr[1]), fmaxf(smr[2], smr[3]));
  __syncthreads();

  float se = (tid < NVT) ? psum[(long)n * NVT + tid] * __expf(m - gm) : 0.f;
#pragma unroll
  for (int mk = 1; mk < 64; mk <<= 1) se += __shfl_xor(se, mk);
  if (lane == 0) smr[w] = se;
  __syncthreads();
  const float gs = smr[0] + smr[1] + smr[2] + smr[3];
  __syncthreads();

#pragma unroll
  for (int mk = 1; mk < 64; mk <<= 1) d += __shfl_xor(d, mk);
  if (lane == 0) smr[w] = d;
  __syncthreads();
  const float gd = smr[0] + smr[1] + smr[2] + smr[3];

  if (tid == 0) {
    nll[n] = valid ? (gm + logf(gs) - gd) : 0.f;
    validf[n] = valid ? 1.f : 0.f;
  }
}

// ---------------- kernel 4: deterministic final mean ----------------

__global__ void final_reduce(const float* __restrict__ nll, const float* __restrict__ validf,
                             float* __restrict__ out, int n) {
  const int tid = threadIdx.x;
  const int lane = tid & 63;
  const int w = tid >> 6;
  __shared__ float sm1[4], sm2[4];
  float s = 0.f, c = 0.f;
  for (int i = tid; i < n; i += blockDim.x) { s += nll[i]; c += validf[i]; }
#pragma unroll
  for (int mk = 1; mk < 64; mk <<= 1) { s += __shfl_xor(s, mk); c += __shfl_xor(c, mk); }
  if (lane == 0) { sm1[w] = s; sm2[w] = c; }
  __syncthreads();
  if (tid == 0) {
    float ts = sm1[0] + sm1[1] + sm1[2] + sm1[3];
    float tc = sm2[0] + sm2[1] + sm2[2] + sm2[3];
    out[0] = ts / fmaxf(tc, 1.0f);
  }
}

// ---------------- launch ----------------

extern "C" void kernel_launch(void* const* d_in, const int* in_sizes, int n_in,
                              void* d_out, int out_size, void* d_ws, size_t ws_size,
                              hipStream_t stream) {
  const float* x = (const float*)d_in[0];     // [8192, 2048] fp32
  const float* wgt = (const float*)d_in[1];   // [32000, 2048] fp32
  const int* tgt = (const int*)d_in[2];       // [8192] int
  float* out = (float*)d_out;

  char* ws = (char*)d_ws;
  const size_t xq_off = 0;
  const size_t wq_off = (size_t)NTOK * DIM;                        // 16,777,216
  const size_t pm_off = wq_off + (size_t)VOC * DIM;                // 82,313,216
  const size_t ps_off = pm_off + (size_t)NTOK * NVT * 4;
  const size_t nl_off = ps_off + (size_t)NTOK * NVT * 4;
  const size_t vf_off = nl_off + (size_t)NTOK * 4;
  const size_t needed = vf_off + (size_t)NTOK * 4;
  if (ws_size < needed) return;  // workspace too small: fail visibly

  unsigned char* xq = (unsigned char*)(ws + xq_off);
  unsigned char* wq = (unsigned char*)(ws + wq_off);
  float* pmax = (float*)(ws + pm_off);
  float* psum = (float*)(ws + ps_off);
  float* nllv = (float*)(ws + nl_off);
  float* vldf = (float*)(ws + vf_off);

  cast_f32_fp8<<<2048, 256, 0, stream>>>(x, xq, (long)NTOK * DIM / 8, 1.0f);
  cast_f32_fp8<<<4096, 256, 0, stream>>>(wgt, wq, (long)VOC * DIM / 8, WSCALE);

  (void)hipFuncSetAttribute((const void*)lce_gemm,
                            hipFuncAttributeMaxDynamicSharedMemorySize, 131072);
  lce_gemm<<<NVT * MT, 512, 131072, stream>>>(xq, wq, pmax, psum);

  token_reduce<<<NTOK, 256, 0, stream>>>(x, wgt, tgt, pmax, psum, nllv, vldf);
  final_reduce<<<1, 256, 0, stream>>>(nllv, vldf, out, NTOK);
}